// Round 3
// baseline (84.584 us; speedup 1.0000x reference)
//
#include <hip/hip_runtime.h>
#include <hip/hip_bf16.h>

#define N_ROWS 10000
#define F_DIM 256
#define J4 2500                      // float4 per row
#define TOTAL_F4 25000000            // N_ROWS * J4
#define LOG2E 1.44269504088896340736f

typedef float f32x4 __attribute__((ext_vector_type(4)));

// Kernel 1: per-row dot products -> e1[i] = exp(-(x@w1 + b)), e2[j] = exp(-(x@w2)).
// 4 waves per block, one row per wave, float4 loads.
__global__ void dot_kernel(const float* __restrict__ x,
                           const float* __restrict__ w,
                           const float* __restrict__ b,
                           float* __restrict__ e1,
                           float* __restrict__ e2) {
    const int wid  = threadIdx.x >> 6;          // wave 0..3
    const int lane = threadIdx.x & 63;
    const int row  = blockIdx.x * 4 + wid;
    const f32x4 xv = reinterpret_cast<const f32x4*>(x + (size_t)row * F_DIM)[lane];
    const f32x4 w1 = reinterpret_cast<const f32x4*>(w)[lane];
    const f32x4 w2 = reinterpret_cast<const f32x4*>(w + F_DIM)[lane];
    float p1 = xv.x * w1.x + xv.y * w1.y + xv.z * w1.z + xv.w * w1.w;
    float p2 = xv.x * w2.x + xv.y * w2.y + xv.z * w2.z + xv.w * w2.w;
    #pragma unroll
    for (int o = 32; o > 0; o >>= 1) {
        p1 += __shfl_xor(p1, o);
        p2 += __shfl_xor(p2, o);
    }
    if (lane == 0) {
        e1[row] = __builtin_amdgcn_exp2f(-(p1 + b[0]) * LOG2E);
        e2[row] = __builtin_amdgcn_exp2f(-p2 * LOG2E);
    }
}

// Kernel 2: out[i][j] = 1 / (1 + e1[i]*e2[j]).
// Flat grid-stride over float4 index space — fillBuffer-shaped contiguous
// store stream, plain (cached) stores.
__global__ void att_kernel(const float* __restrict__ e1,
                           const float* __restrict__ e2,
                           float* __restrict__ out) {
    const unsigned stride = gridDim.x * blockDim.x;
    f32x4* __restrict__ o4 = reinterpret_cast<f32x4*>(out);
    for (unsigned idx = blockIdx.x * blockDim.x + threadIdx.x;
         idx < TOTAL_F4; idx += stride) {
        const unsigned i   = idx / 2500u;        // magic-mul
        const unsigned rem = idx - i * 2500u;
        const float a = e1[i];
        const f32x4 ev = reinterpret_cast<const f32x4*>(e2)[rem];
        f32x4 o;
        o.x = __builtin_amdgcn_rcpf(fmaf(a, ev.x, 1.0f));
        o.y = __builtin_amdgcn_rcpf(fmaf(a, ev.y, 1.0f));
        o.z = __builtin_amdgcn_rcpf(fmaf(a, ev.z, 1.0f));
        o.w = __builtin_amdgcn_rcpf(fmaf(a, ev.w, 1.0f));
        o4[idx] = o;
    }
}

extern "C" void kernel_launch(void* const* d_in, const int* in_sizes, int n_in,
                              void* d_out, int out_size, void* d_ws, size_t ws_size,
                              hipStream_t stream) {
    const float* x = (const float*)d_in[0];
    // d_in[1] = adj (unused by the reference output)
    const float* w = (const float*)d_in[2];
    const float* b = (const float*)d_in[3];
    float* out = (float*)d_out;

    float* e1 = (float*)d_ws;               // N_ROWS floats
    float* e2 = e1 + N_ROWS;                // N_ROWS floats

    dot_kernel<<<N_ROWS / 4, 256, 0, stream>>>(x, w, b, e1, e2);

    att_kernel<<<4096, 256, 0, stream>>>(e1, e2, out);
}